// Round 12
// baseline (592.189 us; speedup 1.0000x reference)
//
#include <hip/hip_runtime.h>

typedef unsigned long long u64;
typedef unsigned int u32;
typedef float v2f __attribute__((ext_vector_type(2)));

// Problem constants (from reference setup_inputs / NUM_GROUP / GROUP_SIZE)
#define BATCH 32
#define NPTS  8192
#define NGRP  512
#define KNN_K 32

#define FPS_T 256                  // block size (uniform)
#define FPS_W (FPS_T / 64)         // 4 waves
#define PPAIR (NPTS / FPS_T / 2)   // 16 point-PAIRS per fps thread
#define KNN_WPB 4                  // knn waves per block
#define QCAP 128                   // per-wave LDS candidate buffer depth

#define FPS_BLOCKS 32
#define KNN_BLOCKS 224
#define TOT_BLOCKS (FPS_BLOCKS + KNN_BLOCKS)
#define CHUNK 16                   // fps center-publish granularity (rounds)
#define TASKS (BATCH * NGRP)       // 16384 knn center-tasks
#define KNN_WAVES (KNN_BLOCKS * KNN_WPB)  // 896 persistent knn waves

// Exact IEEE (no FMA contraction) squared distance: ((dx*dx + dy*dy) + dz*dz)
__device__ __forceinline__ float sq3(float dx, float dy, float dz) {
    return __fadd_rn(__fadd_rn(__fmul_rn(dx, dx), __fmul_rn(dy, dy)), __fmul_rn(dz, dz));
}

// d >= 0 always -> IEEE bits order-monotonic; u64 ascending == (d, idx) lex.
__device__ __forceinline__ u64 packdi(float d, int n) {
    return ((u64)__float_as_uint(d) << 32) | (u32)n;
}

__device__ __forceinline__ u64 umin64(u64 a, u64 b) { return a < b ? a : b; }
__device__ __forceinline__ u64 umax64(u64 a, u64 b) { return a > b ? a : b; }

__device__ __forceinline__ u64 shfl_xor_u64(u64 v, int m) {
    int lo = __shfl_xor((int)(u32)v, m, 64);
    int hi = __shfl_xor((int)(u32)(v >> 32), m, 64);
    return ((u64)(u32)hi << 32) | (u32)lo;
}

__device__ __forceinline__ u64 shfl_u64(u64 v, int src) {
    int lo = __shfl((int)(u32)v, src, 64);
    int hi = __shfl((int)(u32)(v >> 32), src, 64);
    return ((u64)(u32)hi << 32) | (u32)lo;
}

// ---- DPP wave-64 u64-max reduction (result valid in lane 63) --------------
// update_dpp(old=0, bound_ctrl=1): invalid-source lanes read 0; 0 is a safe
// identity (real keys have low32 = ~n >= 0xFFFFE000 > 0).
template <int CTRL>
__device__ __forceinline__ u64 dpp_max_step(u64 k) {
    u32 plo = (u32)__builtin_amdgcn_update_dpp(0, (int)(u32)k, CTRL, 0xF, 0xF, true);
    u32 phi = (u32)__builtin_amdgcn_update_dpp(0, (int)(u32)(k >> 32), CTRL, 0xF, 0xF, true);
    u64 p = ((u64)phi << 32) | plo;
    return k > p ? k : p;
}
__device__ __forceinline__ u64 dpp_wave_max(u64 k) {
    k = dpp_max_step<0x111>(k);  // row_shr:1
    k = dpp_max_step<0x112>(k);  // row_shr:2
    k = dpp_max_step<0x114>(k);  // row_shr:4
    k = dpp_max_step<0x118>(k);  // row_shr:8
    k = dpp_max_step<0x142>(k);  // row_bcast15
    k = dpp_max_step<0x143>(k);  // row_bcast31 -> lane63 = full wave
    return k;
}

// Cross-lane bitonic sort: one u64 per lane -> ascending by lane index.
__device__ __forceinline__ u64 lane_sort64(u64 v, int lane) {
#pragma unroll
    for (int k = 2; k <= 64; k <<= 1) {
#pragma unroll
        for (int j = k >> 1; j > 0; j >>= 1) {
            u64 p = shfl_xor_u64(v, j);
            bool keepmin = (((lane & k) == 0) == ((lane & j) == 0));
            u64 mn = umin64(v, p), mx = umax64(v, p);
            v = keepmin ? mn : mx;
        }
    }
    return v;
}

// m, c ascending-sorted across lanes -> lowest 64 of the 128, sorted.
__device__ __forceinline__ u64 lane_merge64(u64 m, u64 c, int lane) {
    u64 cr = shfl_xor_u64(c, 63);
    u64 z = umin64(m, cr);
#pragma unroll
    for (int dd = 32; dd > 0; dd >>= 1) {
        u64 p = shfl_xor_u64(z, dd);
        u64 mn = umin64(z, p), mx = umax64(z, p);
        z = (lane & dd) ? mx : mn;
    }
    return z;
}

// One knn scan step: tau-filter + ballot-compacted LDS append + batched flush
__device__ __forceinline__ void knn_step(u64& m, u64& tau, int& cnt, u64* sbuf,
                                         float x, float y, float z,
                                         float cx, float cy, float cz,
                                         int n, int lane) {
    float d = sq3(__fsub_rn(x, cx), __fsub_rn(y, cy), __fsub_rn(z, cz));
    u64 kk = packdi(d, n);
    bool cand = kk < tau;  // strict: excluded keys provably > global 32nd
    u64 mask = __ballot(cand);
    if (mask) {
        u32 below = __builtin_amdgcn_mbcnt_hi(
            (u32)(mask >> 32), __builtin_amdgcn_mbcnt_lo((u32)mask, 0));
        if (cand) sbuf[cnt + below] = kk;
        cnt += (int)__popcll(mask);
        if (cnt >= 64) {
            u64 c = sbuf[lane];
            c = lane_sort64(c, lane);
            m = lane_merge64(m, c, lane);
            tau = shfl_u64(m, 31);
            int rem = cnt - 64;
            if (lane < rem) sbuf[lane] = sbuf[64 + lane];
            cnt = rem;
        }
    }
}

struct FpsS {
    float sx[NPTS], sy[NPTS], sz[NPTS];   // 96 KB point mirror
    u64 s_key[2][FPS_W];                  // double-buffered wave partials
    float s_out[NGRP * 3];                // 6 KB center buffer
};
struct KnnS { u64 sbuf[KNN_WPB][QCAP]; };
union SmemU { FpsS f; KnnS k; };

// ---------------------------------------------------------------------------
// Fused producer-consumer kernel (cooperative launch; 1 block/CU by LDS).
// Blocks 0..31: champion FPS (R4/R11 structure, 418 us). Every CHUNK rounds
// wave 0 publishes 48 center floats via agent-scope relaxed atomic stores
// (coherent; bypass per-XCD L2) + t0 release-stores prog[b] (vmcnt drain +
// wbl2 -- writeback only, cached read-only point data unaffected).
// Blocks 32..255: 896 persistent knn waves; task tau -> (r=tau>>5, b=tau&31)
// follows production order. Spin on prog[b] (relaxed agent atomic, s_sleep
// throttled), read center via 3 agent-scope atomic loads (in-order issue +
// completed-before-flag stores => safe without acquire fence; compiler
// barrier stops hoisting). Core: R8 wave-cooperative exact top-32 with
// 4-column unrolled scan (12 hoisted loads -> 4x MLP at 1 wave/SIMD).
// ---------------------------------------------------------------------------
__global__ __launch_bounds__(FPS_T) void fused_kernel(const float* __restrict__ in,
                                                      float* __restrict__ gcent,
                                                      float* __restrict__ out,
                                                      u32* __restrict__ prog) {
    __shared__ SmemU smem;
    const int t = threadIdx.x;
    const int lane = t & 63;

    if (blockIdx.x < FPS_BLOCKS) {
        // ================= FPS producer =================
#pragma clang fp contract(off)
        float* sx = smem.f.sx;
        float* sy = smem.f.sy;
        float* sz = smem.f.sz;
        float* s_out = smem.f.s_out;
        const int b = blockIdx.x;
        const int w = t >> 6;
        const float* xp = in + (size_t)b * 3 * NPTS;
        const float* yp = xp + NPTS;
        const float* zp = xp + 2 * NPTS;
        float* cdst = gcent + (size_t)b * NGRP * 3;

        v2f xr[PPAIR], yr[PPAIR], zr[PPAIR], md[PPAIR];
#pragma unroll
        for (int i = 0; i < PPAIR; ++i) {
            int n = i * (2 * FPS_T) + 2 * t;
            xr[i] = *(const v2f*)(xp + n);
            yr[i] = *(const v2f*)(yp + n);
            zr[i] = *(const v2f*)(zp + n);
            *(v2f*)(sx + n) = xr[i];
            *(v2f*)(sy + n) = yr[i];
            *(v2f*)(sz + n) = zr[i];
            md[i] = (v2f){1e10f, 1e10f};
        }
        __syncthreads();

        int cur = 0;
        for (int r = 0; r < NGRP; ++r) {
            const float cx = sx[cur], cy = sy[cur], cz = sz[cur];
            if (t == 0) {  // idxs[r] = PRE-update farthest -> buffer coords
                s_out[r * 3 + 0] = cx;
                s_out[r * 3 + 1] = cy;
                s_out[r * 3 + 2] = cz;
            }
            float bd0 = -1.0f, bd1 = -1.0f;
            int   bi0 = 0,     bi1 = 0;
#pragma unroll
            for (int i = 0; i < PPAIR; ++i) {
                v2f dx = xr[i] - cx;
                v2f dy = yr[i] - cy;
                v2f dz = zr[i] - cz;
                v2f dd = dx * dx + dy * dy + dz * dz;  // 3 mul + 2 add, per-op IEEE
                md[i] = __builtin_elementwise_min(md[i], dd);
                int n = i * (2 * FPS_T) + 2 * t;
                if (md[i].x > bd0) { bd0 = md[i].x; bi0 = n; }
                if (md[i].y > bd1) { bd1 = md[i].y; bi1 = n + 1; }
            }
            u64 k0 = ((u64)__float_as_uint(bd0) << 32) | (u32)(~(u32)bi0);
            u64 k1 = ((u64)__float_as_uint(bd1) << 32) | (u32)(~(u32)bi1);
            u64 k = dpp_wave_max(umax64(k0, k1));
            if (lane == 63) smem.f.s_key[r & 1][w] = k;
            __syncthreads();
            u64 m = umax64(umax64(smem.f.s_key[r & 1][0], smem.f.s_key[r & 1][1]),
                           umax64(smem.f.s_key[r & 1][2], smem.f.s_key[r & 1][3]));
            cur = (int)(~(u32)m);

            // chunk publish (wave 0 only; hidden under other waves' compute)
            if ((r & (CHUNK - 1)) == (CHUNK - 1) && t < 64) {
                int g = r >> 4;
                if (t < CHUNK * 3) {
                    float v = s_out[g * (CHUNK * 3) + t];
                    __hip_atomic_store((u32*)&cdst[g * (CHUNK * 3) + t],
                                       __float_as_uint(v), __ATOMIC_RELAXED,
                                       __HIP_MEMORY_SCOPE_AGENT);
                }
                if (t == 0)
                    __hip_atomic_store(&prog[b], (u32)(r + 1), __ATOMIC_RELEASE,
                                       __HIP_MEMORY_SCOPE_AGENT);
            }
        }
    } else {
        // ================= kNN consumers =================
        const int blk = blockIdx.x - FPS_BLOCKS;
        const int wave = t >> 6;
        const int wid = blk * KNN_WPB + wave;
        u64* sbuf = smem.k.sbuf[wave];

        for (int tau_t = wid; tau_t < TASKS; tau_t += KNN_WAVES) {
            const int r = tau_t >> 5;
            const int b = tau_t & 31;
            const int cid = (b << 9) + r;
            const float* xp = in + (size_t)b * 3 * NPTS;
            const float* yp = xp + NPTS;
            const float* zp = xp + 2 * NPTS;

            // wait for center r of batch b
            int pv = 0;
            if (lane == 0)
                pv = (int)__hip_atomic_load(&prog[b], __ATOMIC_RELAXED,
                                            __HIP_MEMORY_SCOPE_AGENT);
            pv = __shfl(pv, 0, 64);
            while (pv <= r) {
                __builtin_amdgcn_s_sleep(16);
                if (lane == 0)
                    pv = (int)__hip_atomic_load(&prog[b], __ATOMIC_RELAXED,
                                                __HIP_MEMORY_SCOPE_AGENT);
                pv = __shfl(pv, 0, 64);
            }
            asm volatile("" ::: "memory");  // no hoisting past the spin
            float ctmp = 0.f;
            if (lane < 3)
                ctmp = __uint_as_float(__hip_atomic_load(
                    (const u32*)&gcent[(size_t)cid * 3 + lane], __ATOMIC_RELAXED,
                    __HIP_MEMORY_SCOPE_AGENT));
            const float cx = __shfl(ctmp, 0, 64);
            const float cy = __shfl(ctmp, 1, 64);
            const float cz = __shfl(ctmp, 2, 64);

            // seed: column 0, exact sorted top-64
            float x = xp[lane], y = yp[lane], z = zp[lane];
            u64 m = packdi(sq3(__fsub_rn(x, cx), __fsub_rn(y, cy), __fsub_rn(z, cz)), lane);
            m = lane_sort64(m, lane);
            u64 tau = shfl_u64(m, 31);
            int cnt = 0;

            // 4-column unrolled scan (12 hoisted loads per chunk)
            int j = 1;
#pragma unroll 1
            for (; j + 3 < NPTS / 64; j += 4) {
                int n0 = j * 64 + lane, n1 = n0 + 64, n2 = n0 + 128, n3 = n0 + 192;
                float x0 = xp[n0], y0 = yp[n0], z0 = zp[n0];
                float x1 = xp[n1], y1 = yp[n1], z1 = zp[n1];
                float x2 = xp[n2], y2 = yp[n2], z2 = zp[n2];
                float x3 = xp[n3], y3 = yp[n3], z3 = zp[n3];
                knn_step(m, tau, cnt, sbuf, x0, y0, z0, cx, cy, cz, n0, lane);
                knn_step(m, tau, cnt, sbuf, x1, y1, z1, cx, cy, cz, n1, lane);
                knn_step(m, tau, cnt, sbuf, x2, y2, z2, cx, cy, cz, n2, lane);
                knn_step(m, tau, cnt, sbuf, x3, y3, z3, cx, cy, cz, n3, lane);
            }
            for (; j < NPTS / 64; ++j) {
                int n = j * 64 + lane;
                knn_step(m, tau, cnt, sbuf, xp[n], yp[n], zp[n], cx, cy, cz, n, lane);
            }
            // drain leftovers (<= 127 keys -> at most 2 batches)
            while (cnt > 0) {
                int take = cnt < 64 ? cnt : 64;
                u64 v = sbuf[lane];
                u64 c = (lane < take) ? v : ~0ull;
                c = lane_sort64(c, lane);
                m = lane_merge64(m, c, lane);
                int rem = cnt - take;
                if (lane < rem) sbuf[lane] = sbuf[64 + lane];
                cnt = rem;
            }
            // lanes 0..31 hold exact global top-32 ascending (== stable top_k)
            if (lane < KNN_K) {
                int n = (int)(u32)m;
                size_t o = (size_t)cid * (KNN_K * 3) + (size_t)lane * 3;
                out[o + 0] = __fsub_rn(xp[n], cx);
                out[o + 1] = __fsub_rn(yp[n], cy);
                out[o + 2] = __fsub_rn(zp[n], cz);
            }
        }
    }
}

extern "C" void kernel_launch(void* const* d_in, const int* in_sizes, int n_in,
                              void* d_out, int out_size, void* d_ws, size_t ws_size,
                              hipStream_t stream) {
    const float* in = (const float*)d_in[0];
    float* out      = (float*)d_out;
    float* gcent    = out + (size_t)BATCH * NGRP * KNN_K * 3;  // centers section
    u32* prog       = (u32*)d_ws;

    hipMemsetAsync(prog, 0, BATCH * sizeof(u32), stream);  // prog[b] = 0

    void* args[] = {(void*)&in, (void*)&gcent, (void*)&out, (void*)&prog};
    hipLaunchCooperativeKernel((const void*)fused_kernel, dim3(TOT_BLOCKS),
                               dim3(FPS_T), args, 0, stream);
}